// Round 6
// baseline (96.092 us; speedup 1.0000x reference)
//
#include <hip/hip_runtime.h>
#include <hip/hip_cooperative_groups.h>

#define CE_T_DEV 5
#define EPS_DEV 1e-6f
#define BLK 256           // 4 waves = 4 rows per block

// butterfly: every lane ends with the full 64-lane sum
__device__ __forceinline__ float wave_bcast_sum(float v) {
#pragma unroll
  for (int m = 1; m < 64; m <<= 1) v += __shfl_xor(v, m, 64);
  return v;
}

__global__ void zero_kernel(float* out) { out[0] = 0.0f; }

// Per-row math (one WAVE per row, one pass over K classes, 5 scalars):
//   lg  = sum_i log(1+e^{d_i})  (= -ignorance_log)
//   sed = sum_i e^{d_i} ;  sq2 = sum_i e^{2 d_i}
//   c_ed = e^{d}@label ;  c_d = d@label
// Closed forms (Se = S*exp(ign)):
//   S_a = Se*sed + K ; sum(alpha^2) = Se^2*sq2 + 2*Se*sed + K
//   err = sa2/S_a^2 - 2*alpha_lab/S_a + 1
//   var = (S_a^2 - sa2)/(S_a^2 (S_a+1))
//   sum_i ce_i = lg - c_d ; belief_gt = c_ed/(1+c_ed) ; pmax = 1-exp(ign)
__device__ __forceinline__ float row_contrib(const float* __restrict__ logits,
                                             const int* __restrict__ labels,
                                             const int* __restrict__ epoch_p,
                                             int row, int B, int K, int lane) {
  const int label = labels[row];
  const float* __restrict__ rp = logits + (size_t)row * (size_t)(2 * K);
  const int pairs = K >> 1;
  const int nf = pairs >> 6;
  const int rem = pairs & 63;

  float lg = 0.f, sed = 0.f, sq2 = 0.f, c_ed = 0.f, c_d = 0.f;

#define BODY(L0, L1, IDX)                                   \
  {                                                         \
    const float d = (L0) - (L1);                            \
    const float ed = __expf(d);                             \
    lg += __logf(1.f + ed);                                 \
    sed += ed;                                              \
    sq2 = fmaf(ed, ed, sq2);                                \
    const bool is = ((IDX) == label);                       \
    c_ed = is ? ed : c_ed;                                  \
    c_d = is ? d : c_d;                                     \
  }

#pragma unroll 2
  for (int i = 0; i < nf; ++i) {
    const int p = (i << 6) + lane;
    const float4 v = *reinterpret_cast<const float4*>(rp + 4 * (size_t)p);
    BODY(v.x, v.y, 2 * p)
    BODY(v.z, v.w, 2 * p + 1)
  }
  if (lane < rem) {
    const int p = (nf << 6) + lane;
    const float4 v = *reinterpret_cast<const float4*>(rp + 4 * (size_t)p);
    BODY(v.x, v.y, 2 * p)
    BODY(v.z, v.w, 2 * p + 1)
  }
  if ((K & 1) && lane == 0) {
    const float l0 = rp[2 * (size_t)(K - 1)];
    const float l1 = rp[2 * (size_t)(K - 1) + 1];
    BODY(l0, l1, K - 1)
  }
#undef BODY

  lg   = wave_bcast_sum(lg);
  sed  = wave_bcast_sum(sed);
  sq2  = wave_bcast_sum(sq2);
  c_ed = wave_bcast_sum(c_ed);   // only owning lane nonzero -> sum == value
  c_d  = wave_bcast_sum(c_d);

  const float ign = -lg;
  const float eign = __expf(ign);
  const float S = (float)K / ((1.f - eign * sed) + EPS_DEV);
  const float Se = S * eign;
  const float S_a = Se * sed + (float)K;
  const float inv_Sa = 1.f / S_a;
  const float sa2 = Se * Se * sq2 + 2.f * Se * sed + (float)K;
  const float alpha_lab = Se * c_ed + 1.f;
  const float err = sa2 * inv_Sa * inv_Sa - 2.f * alpha_lab * inv_Sa + 1.f;
  const float var = (S_a * S_a - sa2) / (S_a * S_a * (S_a + 1.f));
  const float bgt = c_ed / (1.f + c_ed);
  const float pmax = 1.f - eign;
  const float edl2 = (bgt - pmax) * (bgt - pmax);
  float contrib = (err + var + edl2) / (float)B;
  if (epoch_p[0] < CE_T_DEV) contrib += (lg - c_d) / ((float)B * (float)K);
  return contrib;
}

// Single cooperative dispatch: per-block partial -> ws[blockIdx], grid.sync,
// block 0 reduces all partials in fixed order -> out[0]. Deterministic.
__global__ __launch_bounds__(BLK) void loss_coop_kernel(
    const float* __restrict__ logits, const int* __restrict__ labels,
    const int* __restrict__ epoch_p, float* __restrict__ ws,
    float* __restrict__ out, int B, int K) {
  const int tid = threadIdx.x;
  const int lane = tid & 63;
  const int wv = tid >> 6;
  constexpr int NW = BLK / 64;
  __shared__ float sm[NW];
  const int row = blockIdx.x * NW + wv;
  const int grid = gridDim.x;

  float c = (row < B) ? row_contrib(logits, labels, epoch_p, row, B, K, lane) : 0.f;
  if (lane == 0) sm[wv] = c;
  __syncthreads();
  if (tid == 0) {
    float s = 0.f;
#pragma unroll
    for (int w = 0; w < NW; ++w) s += sm[w];
    ws[blockIdx.x] = s;
  }
  cooperative_groups::this_grid().sync();

  if (blockIdx.x == 0) {
    float acc = 0.f;
    for (int i = tid; i < grid; i += BLK) acc += ws[i];
    acc = wave_bcast_sum(acc);
    if (lane == 0) sm[wv] = acc;
    __syncthreads();
    if (tid == 0) {
      float s = 0.f;
#pragma unroll
      for (int w = 0; w < NW; ++w) s += sm[w];
      out[0] = s;
    }
  }
}

// Fallback two-dispatch path (proven R5 structure).
template <bool USE_WS>
__global__ __launch_bounds__(BLK) void loss_kernel(
    const float* __restrict__ logits, const int* __restrict__ labels,
    const int* __restrict__ epoch_p, float* __restrict__ row_out, int B, int K) {
  const int tid = threadIdx.x;
  const int lane = tid & 63;
  const int wv = tid >> 6;
  constexpr int NW = BLK / 64;
  const int row = blockIdx.x * NW + wv;
  if (row >= B) return;
  float c = row_contrib(logits, labels, epoch_p, row, B, K, lane);
  if (lane == 0) {
    if (USE_WS) row_out[row] = c;
    else        atomicAdd(row_out, c);
  }
}

__global__ __launch_bounds__(256) void reduce_kernel(const float* __restrict__ ws,
                                                     float* __restrict__ out, int B) {
  const int tid = threadIdx.x;
  const int lane = tid & 63;
  const int wv = tid >> 6;
  __shared__ float sm[4];
  float acc = 0.f;
  for (int i = tid; i < B; i += 256) acc += ws[i];
  acc = wave_bcast_sum(acc);
  if (lane == 0) sm[wv] = acc;
  __syncthreads();
  if (tid == 0) out[0] = sm[0] + sm[1] + sm[2] + sm[3];
}

extern "C" void kernel_launch(void* const* d_in, const int* in_sizes, int n_in,
                              void* d_out, int out_size, void* d_ws, size_t ws_size,
                              hipStream_t stream) {
  const float* logits = (const float*)d_in[0];
  const int* labels = (const int*)d_in[1];
  const int* epoch = (const int*)d_in[2];
  float* out = (float*)d_out;

  const int B = in_sizes[1];
  const int K = in_sizes[0] / (2 * B);
  constexpr int ROWS_PER_BLK = BLK / 64;
  int grid = (B + ROWS_PER_BLK - 1) / ROWS_PER_BLK;

  // Cooperative single-dispatch path: needs ws for per-block partials and
  // grid within co-residency bound (256 CU * 8 blocks of 256 thr = 2048).
  if (ws_size >= (size_t)grid * sizeof(float) && grid <= 2048) {
    float* ws = (float*)d_ws;
    void* args[] = {(void*)&logits, (void*)&labels, (void*)&epoch,
                    (void*)&ws, (void*)&out, (void*)&B, (void*)&K};
    hipError_t e = hipLaunchCooperativeKernel((const void*)loss_coop_kernel,
                                              dim3(grid), dim3(BLK), args, 0, stream);
    if (e == hipSuccess) return;
  }
  // Fallback: two dispatches.
  if (ws_size >= (size_t)B * sizeof(float)) {
    float* ws = (float*)d_ws;
    loss_kernel<true><<<grid, BLK, 0, stream>>>(logits, labels, epoch, ws, B, K);
    reduce_kernel<<<1, 256, 0, stream>>>(ws, out, B);
  } else {
    zero_kernel<<<1, 64, 0, stream>>>(out);
    loss_kernel<false><<<grid, BLK, 0, stream>>>(logits, labels, epoch, out, B, K);
  }
}

// Round 7
// 26.599 us; speedup vs baseline: 3.6127x; 3.6127x over previous
//
#include <hip/hip_runtime.h>
#include <hip/hip_bf16.h>

#define CE_T_DEV 5
#define EPS_DEV 1e-6f
#define BLK 256           // 4 waves = 4 rows per block
#define LN2F 0.69314718056f

// butterfly: every lane ends with the full 64-lane sum
__device__ __forceinline__ float wave_bcast_sum(float v) {
#pragma unroll
  for (int m = 1; m < 64; m <<= 1) v += __shfl_xor(v, m, 64);
  return v;
}

__global__ void zero_kernel(float* out) { out[0] = 0.0f; }

// One WAVE per row, one pass over K classes, 3 wave-reduced scalars:
//   l2g = sum_i log2(1+e^{d_i})   (lg = ln2*l2g = -ignorance_log)
//   sed = sum_i e^{d_i} ;  sq2 = sum_i e^{2 d_i}
// Label terms via direct broadcast load (no per-class selects):
//   c_d = l0[label]-l1[label] ; c_ed = e^{c_d}
// Closed forms (Se = S*exp(ign)):
//   S_a = Se*sed + K ; sa2 = Se^2*sq2 + 2*Se*sed + K    (= sum alpha^2)
//   err = sa2/S_a^2 - 2*alpha_lab/S_a + 1
//   var = (S_a^2 - sa2)/(S_a^2 (S_a+1))
//   sum_i ce_i = lg - c_d ; belief_gt = c_ed/(1+c_ed) ; pmax = 1-exp(ign)
template <bool ATOMIC>
__global__ __launch_bounds__(BLK) void loss_kernel(
    const float* __restrict__ logits,
    const int* __restrict__ labels,
    const int* __restrict__ epoch_p,
    float* __restrict__ out,       // ATOMIC: out[0] (pre-zeroed); else ws[B]
    int B, int K) {
  const int tid = threadIdx.x;
  const int lane = tid & 63;
  const int wv = tid >> 6;
  constexpr int NW = BLK / 64;
  __shared__ float sm[NW];
  const int row = blockIdx.x * NW + wv;

  float contrib = 0.f;
  if (row < B) {
    const int label = labels[row];
    const float* __restrict__ rp = logits + (size_t)row * (size_t)(2 * K);
    // broadcast load of the label's logit pair, issued ahead of the loop
    const float lab0 = rp[2 * (size_t)label];
    const float lab1 = rp[2 * (size_t)label + 1];
    const int pairs = K >> 1;
    const int nf = pairs >> 6;
    const int rem = pairs & 63;

    float l2g = 0.f, sed = 0.f, sq2 = 0.f;

#define BODY(L0, L1)                                        \
    {                                                       \
      const float d = (L0) - (L1);                          \
      const float ed = __expf(d);                           \
      l2g += __log2f(1.f + ed);                             \
      sed += ed;                                            \
      sq2 = fmaf(ed, ed, sq2);                              \
    }

#pragma unroll 4
    for (int i = 0; i < nf; ++i) {
      const int p = (i << 6) + lane;
      const float4 v = *reinterpret_cast<const float4*>(rp + 4 * (size_t)p);
      BODY(v.x, v.y)
      BODY(v.z, v.w)
    }
    if (lane < rem) {
      const int p = (nf << 6) + lane;
      const float4 v = *reinterpret_cast<const float4*>(rp + 4 * (size_t)p);
      BODY(v.x, v.y)
      BODY(v.z, v.w)
    }
    if ((K & 1) && lane == 0) {     // odd-K tail (unused for K=1000)
      const float l0 = rp[2 * (size_t)(K - 1)];
      const float l1 = rp[2 * (size_t)(K - 1) + 1];
      BODY(l0, l1)
    }
#undef BODY

    l2g = wave_bcast_sum(l2g);
    sed = wave_bcast_sum(sed);
    sq2 = wave_bcast_sum(sq2);

    const float lg = LN2F * l2g;           // sum log(1+e^d) = -ignorance_log
    const float c_d = lab0 - lab1;
    const float c_ed = __expf(c_d);
    const float eign = __expf(-lg);
    const float S = (float)K / ((1.f - eign * sed) + EPS_DEV);
    const float Se = S * eign;
    const float S_a = Se * sed + (float)K;
    const float inv_Sa = 1.f / S_a;
    const float sa2 = Se * Se * sq2 + 2.f * Se * sed + (float)K;
    const float alpha_lab = Se * c_ed + 1.f;
    const float err = sa2 * inv_Sa * inv_Sa - 2.f * alpha_lab * inv_Sa + 1.f;
    const float var = (S_a * S_a - sa2) / (S_a * S_a * (S_a + 1.f));
    const float bgt = c_ed / (1.f + c_ed);          // plausibility @ label
    const float pmax = 1.f - eign;
    const float edl2 = (bgt - pmax) * (bgt - pmax);
    contrib = (err + var + edl2) / (float)B;
    if (epoch_p[0] < CE_T_DEV) contrib += (lg - c_d) / ((float)B * (float)K);
  }

  if (ATOMIC) {
    if (lane == 0) sm[wv] = contrib;
    __syncthreads();
    if (tid == 0) {
      float s = 0.f;
#pragma unroll
      for (int w = 0; w < NW; ++w) s += sm[w];
      atomicAdd(out, s);
    }
  } else {
    if (row < B && lane == 0) out[row] = contrib;
  }
}

__global__ __launch_bounds__(256) void reduce_kernel(const float* __restrict__ ws,
                                                     float* __restrict__ out, int B) {
  const int tid = threadIdx.x;
  const int lane = tid & 63;
  const int wv = tid >> 6;
  __shared__ float sm[4];
  float acc = 0.f;
  for (int i = tid; i < B; i += 256) acc += ws[i];
  acc = wave_bcast_sum(acc);
  if (lane == 0) sm[wv] = acc;
  __syncthreads();
  if (tid == 0) out[0] = sm[0] + sm[1] + sm[2] + sm[3];
}

extern "C" void kernel_launch(void* const* d_in, const int* in_sizes, int n_in,
                              void* d_out, int out_size, void* d_ws, size_t ws_size,
                              hipStream_t stream) {
  const float* logits = (const float*)d_in[0];
  const int* labels = (const int*)d_in[1];
  const int* epoch = (const int*)d_in[2];
  float* out = (float*)d_out;

  const int B = in_sizes[1];
  const int K = in_sizes[0] / (2 * B);
  constexpr int ROWS_PER_BLK = BLK / 64;
  const int grid = (B + ROWS_PER_BLK - 1) / ROWS_PER_BLK;

  // Primary: 4-byte memset node + single loss kernel with per-block atomicAdd.
  hipError_t e = hipMemsetAsync(d_out, 0, sizeof(float), stream);
  if (e == hipSuccess) {
    loss_kernel<true><<<grid, BLK, 0, stream>>>(logits, labels, epoch, out, B, K);
    return;
  }
  // Fallback: two-kernel deterministic path (R5 structure).
  if (ws_size >= (size_t)B * sizeof(float)) {
    float* ws = (float*)d_ws;
    loss_kernel<false><<<grid, BLK, 0, stream>>>(logits, labels, epoch, ws, B, K);
    reduce_kernel<<<1, 256, 0, stream>>>(ws, out, B);
  } else {
    zero_kernel<<<1, 64, 0, stream>>>(out);
    loss_kernel<true><<<grid, BLK, 0, stream>>>(logits, labels, epoch, out, B, K);
  }
}

// Round 8
// 16.673 us; speedup vs baseline: 5.7632x; 1.5953x over previous
//
#include <hip/hip_runtime.h>
#include <hip/hip_bf16.h>

#define CE_T_DEV 5
#define EPS_DEV 1e-6f
#define BLK 256           // 4 waves = 4 rows per block
#define LN2F 0.69314718056f

// butterfly: every lane ends with the full 64-lane sum
__device__ __forceinline__ float wave_bcast_sum(float v) {
#pragma unroll
  for (int m = 1; m < 64; m <<= 1) v += __shfl_xor(v, m, 64);
  return v;
}

__global__ void zero_kernel(float* out) { out[0] = 0.0f; }

// One WAVE per row, one pass over K classes, 3 wave-reduced scalars:
//   l2g = sum_i log2(1+e^{d_i})   (lg = ln2*l2g = -ignorance_log)
//   sed = sum_i e^{d_i} ;  sq2 = sum_i e^{2 d_i}
// Label terms via direct broadcast load (no per-class selects):
//   c_d = l0[label]-l1[label] ; c_ed = e^{c_d}
// Closed forms (Se = S*exp(ign)):
//   S_a = Se*sed + K ; sa2 = Se^2*sq2 + 2*Se*sed + K    (= sum alpha^2)
//   err = sa2/S_a^2 - 2*alpha_lab/S_a + 1
//   var = (S_a^2 - sa2)/(S_a^2 (S_a+1))
//   sum_i ce_i = lg - c_d ; belief_gt = c_ed/(1+c_ed) ; pmax = 1-exp(ign)
template <bool PARTIALS>   // true: ws[blockIdx] partial; false: atomicAdd(out)
__global__ __launch_bounds__(BLK) void loss_kernel(
    const float* __restrict__ logits,
    const int* __restrict__ labels,
    const int* __restrict__ epoch_p,
    float* __restrict__ out,
    int B, int K) {
  const int tid = threadIdx.x;
  const int lane = tid & 63;
  const int wv = tid >> 6;
  constexpr int NW = BLK / 64;
  __shared__ float sm[NW];
  const int row = blockIdx.x * NW + wv;

  float contrib = 0.f;
  if (row < B) {
    const int label = labels[row];
    const float* __restrict__ rp = logits + (size_t)row * (size_t)(2 * K);
    // broadcast load of the label's logit pair, issued ahead of the loop
    const float lab0 = rp[2 * (size_t)label];
    const float lab1 = rp[2 * (size_t)label + 1];
    const int pairs = K >> 1;
    const int nf = pairs >> 6;
    const int rem = pairs & 63;

    float l2g = 0.f, sed = 0.f, sq2 = 0.f;

#define BODY(L0, L1)                                        \
    {                                                       \
      const float d = (L0) - (L1);                          \
      const float ed = __expf(d);                           \
      l2g += __log2f(1.f + ed);                             \
      sed += ed;                                            \
      sq2 = fmaf(ed, ed, sq2);                              \
    }

#pragma unroll 4
    for (int i = 0; i < nf; ++i) {
      const int p = (i << 6) + lane;
      const float4 v = *reinterpret_cast<const float4*>(rp + 4 * (size_t)p);
      BODY(v.x, v.y)
      BODY(v.z, v.w)
    }
    if (lane < rem) {
      const int p = (nf << 6) + lane;
      const float4 v = *reinterpret_cast<const float4*>(rp + 4 * (size_t)p);
      BODY(v.x, v.y)
      BODY(v.z, v.w)
    }
    if ((K & 1) && lane == 0) {     // odd-K tail (unused for K=1000)
      const float l0 = rp[2 * (size_t)(K - 1)];
      const float l1 = rp[2 * (size_t)(K - 1) + 1];
      BODY(l0, l1)
    }
#undef BODY

    l2g = wave_bcast_sum(l2g);
    sed = wave_bcast_sum(sed);
    sq2 = wave_bcast_sum(sq2);

    const float lg = LN2F * l2g;           // sum log(1+e^d) = -ignorance_log
    const float c_d = lab0 - lab1;
    const float c_ed = __expf(c_d);
    const float eign = __expf(-lg);
    const float S = (float)K / ((1.f - eign * sed) + EPS_DEV);
    const float Se = S * eign;
    const float S_a = Se * sed + (float)K;
    const float inv_Sa = 1.f / S_a;
    const float sa2 = Se * Se * sq2 + 2.f * Se * sed + (float)K;
    const float alpha_lab = Se * c_ed + 1.f;
    const float err = sa2 * inv_Sa * inv_Sa - 2.f * alpha_lab * inv_Sa + 1.f;
    const float var = (S_a * S_a - sa2) / (S_a * S_a * (S_a + 1.f));
    const float bgt = c_ed / (1.f + c_ed);          // plausibility @ label
    const float pmax = 1.f - eign;
    const float edl2 = (bgt - pmax) * (bgt - pmax);
    contrib = (err + var + edl2) / (float)B;
    if (epoch_p[0] < CE_T_DEV) contrib += (lg - c_d) / ((float)B * (float)K);
  }

  if (lane == 0) sm[wv] = contrib;
  __syncthreads();
  if (tid == 0) {
    float s = 0.f;
#pragma unroll
    for (int w = 0; w < NW; ++w) s += sm[w];
    if (PARTIALS) out[blockIdx.x] = s;
    else          atomicAdd(out, s);
  }
}

__global__ __launch_bounds__(256) void reduce_kernel(const float* __restrict__ ws,
                                                     float* __restrict__ out, int n) {
  const int tid = threadIdx.x;
  const int lane = tid & 63;
  const int wv = tid >> 6;
  __shared__ float sm[4];
  float acc = 0.f;
  for (int i = tid; i < n; i += 256) acc += ws[i];
  acc = wave_bcast_sum(acc);
  if (lane == 0) sm[wv] = acc;
  __syncthreads();
  if (tid == 0) out[0] = sm[0] + sm[1] + sm[2] + sm[3];
}

extern "C" void kernel_launch(void* const* d_in, const int* in_sizes, int n_in,
                              void* d_out, int out_size, void* d_ws, size_t ws_size,
                              hipStream_t stream) {
  const float* logits = (const float*)d_in[0];
  const int* labels = (const int*)d_in[1];
  const int* epoch = (const int*)d_in[2];
  float* out = (float*)d_out;

  const int B = in_sizes[1];
  const int K = in_sizes[0] / (2 * B);
  constexpr int ROWS_PER_BLK = BLK / 64;
  const int grid = (B + ROWS_PER_BLK - 1) / ROWS_PER_BLK;

  if (ws_size >= (size_t)grid * sizeof(float)) {
    float* ws = (float*)d_ws;
    loss_kernel<true><<<grid, BLK, 0, stream>>>(logits, labels, epoch, ws, B, K);
    reduce_kernel<<<1, 256, 0, stream>>>(ws, out, grid);
  } else {
    zero_kernel<<<1, 64, 0, stream>>>(out);
    loss_kernel<false><<<grid, BLK, 0, stream>>>(logits, labels, epoch, out, B, K);
  }
}

// Round 9
// 12.938 us; speedup vs baseline: 7.4270x; 1.2887x over previous
//
#include <hip/hip_runtime.h>
#include <hip/hip_bf16.h>

#define CE_T_DEV 5
#define EPS_DEV 1e-6f
#define BLK 1024          // 16 waves = 16 rows per block; grid = B/16 = 256 = 1 block/CU
#define LN2F 0.69314718056f

// butterfly: every lane ends with the full 64-lane sum
__device__ __forceinline__ float wave_bcast_sum(float v) {
#pragma unroll
  for (int m = 1; m < 64; m <<= 1) v += __shfl_xor(v, m, 64);
  return v;
}

__global__ void zero_kernel(float* out) { out[0] = 0.0f; }

// One WAVE per row, one pass over K classes, 3 wave-reduced scalars:
//   l2g = sum_i log2(1+e^{d_i})   (lg = ln2*l2g = -ignorance_log)
//   sed = sum_i e^{d_i} ;  sq2 = sum_i e^{2 d_i}
// Label terms via direct broadcast load: c_d = l0[lab]-l1[lab] ; c_ed = e^{c_d}
// Closed forms (Se = S*exp(ign)):
//   S_a = Se*sed + K ; sa2 = Se^2*sq2 + 2*Se*sed + K    (= sum alpha^2)
//   err = sa2/S_a^2 - 2*alpha_lab/S_a + 1
//   var = (S_a^2 - sa2)/(S_a^2 (S_a+1))
//   sum_i ce_i = lg - c_d ; belief_gt = c_ed/(1+c_ed) ; pmax = 1-exp(ign)
template <bool PARTIALS>   // true: ws[blockIdx] partial; false: atomicAdd(out)
__global__ __launch_bounds__(BLK) void loss_kernel(
    const float* __restrict__ logits,
    const int* __restrict__ labels,
    const int* __restrict__ epoch_p,
    float* __restrict__ out,
    int B, int K) {
  const int tid = threadIdx.x;
  const int lane = tid & 63;
  const int wv = tid >> 6;
  constexpr int NW = BLK / 64;
  __shared__ float sm[NW];
  const int row = blockIdx.x * NW + wv;

  float contrib = 0.f;
  if (row < B) {
    const int label = labels[row];
    const float* __restrict__ rp = logits + (size_t)row * (size_t)(2 * K);
    // broadcast load of the label's logit pair, issued ahead of the loop
    const float lab0 = rp[2 * (size_t)label];
    const float lab1 = rp[2 * (size_t)label + 1];
    const int pairs = K >> 1;
    const int nf = pairs >> 6;
    const int rem = pairs & 63;

    float l2g = 0.f, sed = 0.f, sq2 = 0.f;

#define BODY(L0, L1)                                        \
    {                                                       \
      const float d = (L0) - (L1);                          \
      const float ed = __expf(d);                           \
      l2g += __log2f(1.f + ed);                             \
      sed += ed;                                            \
      sq2 = fmaf(ed, ed, sq2);                              \
    }

#pragma unroll 4
    for (int i = 0; i < nf; ++i) {
      const int p = (i << 6) + lane;
      const float4 v = *reinterpret_cast<const float4*>(rp + 4 * (size_t)p);
      BODY(v.x, v.y)
      BODY(v.z, v.w)
    }
    if (lane < rem) {
      const int p = (nf << 6) + lane;
      const float4 v = *reinterpret_cast<const float4*>(rp + 4 * (size_t)p);
      BODY(v.x, v.y)
      BODY(v.z, v.w)
    }
    if ((K & 1) && lane == 0) {     // odd-K tail (unused for K=1000)
      const float l0 = rp[2 * (size_t)(K - 1)];
      const float l1 = rp[2 * (size_t)(K - 1) + 1];
      BODY(l0, l1)
    }
#undef BODY

    l2g = wave_bcast_sum(l2g);
    sed = wave_bcast_sum(sed);
    sq2 = wave_bcast_sum(sq2);

    const float lg = LN2F * l2g;           // sum log(1+e^d) = -ignorance_log
    const float c_d = lab0 - lab1;
    const float c_ed = __expf(c_d);
    const float eign = __expf(-lg);
    const float S = (float)K / ((1.f - eign * sed) + EPS_DEV);
    const float Se = S * eign;
    const float S_a = Se * sed + (float)K;
    const float inv_Sa = 1.f / S_a;
    const float sa2 = Se * Se * sq2 + 2.f * Se * sed + (float)K;
    const float alpha_lab = Se * c_ed + 1.f;
    const float err = sa2 * inv_Sa * inv_Sa - 2.f * alpha_lab * inv_Sa + 1.f;
    const float var = (S_a * S_a - sa2) / (S_a * S_a * (S_a + 1.f));
    const float bgt = c_ed / (1.f + c_ed);          // plausibility @ label
    const float pmax = 1.f - eign;
    const float edl2 = (bgt - pmax) * (bgt - pmax);
    contrib = (err + var + edl2) / (float)B;
    if (epoch_p[0] < CE_T_DEV) contrib += (lg - c_d) / ((float)B * (float)K);
  }

  if (lane == 0) sm[wv] = contrib;
  __syncthreads();
  if (tid == 0) {
    float s = 0.f;
#pragma unroll
    for (int w = 0; w < NW; ++w) s += sm[w];
    if (PARTIALS) out[blockIdx.x] = s;
    else          atomicAdd(out, s);
  }
}

// single-wave final reduce: no LDS, no __syncthreads, one memory round-trip
__global__ __launch_bounds__(64) void reduce_kernel(const float* __restrict__ ws,
                                                    float* __restrict__ out, int n) {
  const int lane = threadIdx.x;
  float acc = 0.f;
  for (int i = lane; i < n; i += 64) acc += ws[i];
  acc = wave_bcast_sum(acc);
  if (lane == 0) out[0] = acc;
}

extern "C" void kernel_launch(void* const* d_in, const int* in_sizes, int n_in,
                              void* d_out, int out_size, void* d_ws, size_t ws_size,
                              hipStream_t stream) {
  const float* logits = (const float*)d_in[0];
  const int* labels = (const int*)d_in[1];
  const int* epoch = (const int*)d_in[2];
  float* out = (float*)d_out;

  const int B = in_sizes[1];
  const int K = in_sizes[0] / (2 * B);
  constexpr int ROWS_PER_BLK = BLK / 64;
  const int grid = (B + ROWS_PER_BLK - 1) / ROWS_PER_BLK;

  if (ws_size >= (size_t)grid * sizeof(float)) {
    float* ws = (float*)d_ws;
    loss_kernel<true><<<grid, BLK, 0, stream>>>(logits, labels, epoch, ws, B, K);
    reduce_kernel<<<1, 64, 0, stream>>>(ws, out, grid);
  } else {
    zero_kernel<<<1, 64, 0, stream>>>(out);
    loss_kernel<false><<<grid, BLK, 0, stream>>>(logits, labels, epoch, out, B, K);
  }
}